// Round 1
// baseline (557.609 us; speedup 1.0000x reference)
//
#include <hip/hip_runtime.h>

#define NPTS 8192      // H*W
#define BCLS 4         // C
#define NP   6         // B*(C-1) pairs
#define R2   9.0f
#define LDS_KEPT 6144  // LDS-staged kept-point cap (overflow spills to global path)

// ---------------------------------------------------------------------------
// Kernel 1: per (b,c) pair, argmax class + order-preserving compaction of
// candidate points (x, y, orig_index).
// ---------------------------------------------------------------------------
__global__ __launch_bounds__(1024) void k_compact(
    const float* __restrict__ seg, const float* __restrict__ lidar,
    float* __restrict__ cand_x, float* __restrict__ cand_y,
    int* __restrict__ cand_i, int* __restrict__ Mcnt)
{
    int p = blockIdx.x;
    int b = p / 3, cls = p % 3 + 1;
    int tid = threadIdx.x;
    int lane = tid & 63, wave = tid >> 6;
    __shared__ int wsum[16];
    __shared__ int sbase;
    if (tid == 0) sbase = 0;
    __syncthreads();
    const float* segb = seg + (size_t)b * BCLS * NPTS;
    const float* lx = lidar + (size_t)b * 2 * NPTS;
    const float* ly = lx + NPTS;
    for (int start = 0; start < NPTS; start += 1024) {
        int n = start + tid;
        // argmax over classes, first index wins on ties (strict >)
        float bv = segb[n];
        int bc = 0;
        #pragma unroll
        for (int c2 = 1; c2 < BCLS; ++c2) {
            float v = segb[c2 * NPTS + n];
            if (v > bv) { bv = v; bc = c2; }
        }
        bool m = (bc == cls);
        unsigned long long bal = __ballot(m);
        int rank = __popcll(bal & ((1ull << lane) - 1ull));
        if (lane == 0) wsum[wave] = __popcll(bal);
        __syncthreads();
        if (tid == 0) {
            int acc = sbase;
            for (int w = 0; w < 16; ++w) { int t = wsum[w]; wsum[w] = acc; acc += t; }
            sbase = acc;
        }
        __syncthreads();
        if (m) {
            int pos = p * NPTS + wsum[wave] + rank;
            cand_x[pos] = lx[n];
            cand_y[pos] = ly[n];
            cand_i[pos] = n;
        }
        __syncthreads();  // protect wsum before next iteration
    }
    if (tid == 0) Mcnt[p] = sbase;
}

// ---------------------------------------------------------------------------
// Kernel 2: greedy radius-NMS per pair. Batched-greedy: chunk of 64 candidates
// checked vs all previously-kept (parallel, 16 sub-lists x 64 candidates),
// then wave 0 resolves intra-chunk order dependencies (steps only over
// surviving candidates) and appends to the kept list.
// ---------------------------------------------------------------------------
__global__ __launch_bounds__(1024) void k_nms(
    const float* __restrict__ cand_x, const float* __restrict__ cand_y,
    const int* __restrict__ cand_i, const int* __restrict__ Mcnt,
    float* __restrict__ kept_x, float* __restrict__ kept_y,
    int* __restrict__ kept_i, int* __restrict__ Kcnt,
    unsigned char* __restrict__ keepf)
{
    int p = blockIdx.x;
    int tid = threadIdx.x;
    int M = Mcnt[p];
    __shared__ float2 skept[LDS_KEPT];   // 48 KB
    __shared__ float scx[64], scy[64];
    __shared__ int sflag[64];
    __shared__ int sK;
    if (tid == 0) sK = 0;
    __syncthreads();
    const int base = p * NPTS;
    for (int start = 0; start < M; start += 64) {
        int csz = min(64, M - start);
        // phase 0: load chunk
        if (tid < 64) {
            sflag[tid] = (tid < csz) ? 1 : 0;
            if (tid < csz) {
                scx[tid] = cand_x[base + start + tid];
                scy[tid] = cand_y[base + start + tid];
            }
        }
        __syncthreads();
        // phase 1: external check vs kept list (all 1024 threads)
        int K = sK;
        int c = tid & 63, sub = tid >> 6;
        if (c < csz) {
            float x = scx[c], y = scy[c];
            int klim = min(K, LDS_KEPT);
            for (int k = sub; k < klim; k += 16) {
                float2 kp = skept[k];
                float dx = __fsub_rn(x, kp.x), dy = __fsub_rn(y, kp.y);
                float d2 = __fadd_rn(__fmul_rn(dx, dx), __fmul_rn(dy, dy));
                if (d2 < R2) { sflag[c] = 0; break; }
            }
            for (int k = LDS_KEPT + sub; k < K; k += 16) {  // LDS overflow path
                float dx = __fsub_rn(x, kept_x[base + k]);
                float dy = __fsub_rn(y, kept_y[base + k]);
                float d2 = __fadd_rn(__fmul_rn(dx, dx), __fmul_rn(dy, dy));
                if (d2 < R2) { sflag[c] = 0; break; }
            }
        }
        __syncthreads();
        // phase 2: intra-chunk resolve + append (wave 0 only)
        if (tid < 64) {
            int lane = tid;
            bool alive = (lane < csz) && (sflag[lane] != 0);
            float x = scx[lane], y = scy[lane];
            unsigned long long aliveMask = __ballot(alive);
            unsigned long long processed = 0ull, pend;
            while ((pend = (aliveMask & ~processed)) != 0ull) {
                int t = __builtin_ctzll(pend);
                processed |= (1ull << t);
                float tx = __shfl(x, t), ty = __shfl(y, t);
                if (alive && lane > t) {
                    float dx = __fsub_rn(x, tx), dy = __fsub_rn(y, ty);
                    float d2 = __fadd_rn(__fmul_rn(dx, dx), __fmul_rn(dy, dy));
                    if (d2 < R2) alive = false;
                }
                aliveMask = __ballot(alive);
            }
            int K0 = sK;
            int rank = __popcll(aliveMask & ((1ull << lane) - 1ull));
            if (alive) {
                int pos = K0 + rank;
                if (pos < LDS_KEPT) skept[pos] = make_float2(x, y);
                kept_x[base + pos] = x;
                kept_y[base + pos] = y;
                int gi = cand_i[base + start + lane];
                kept_i[base + pos] = gi;
                keepf[base + gi] = 1;
            }
            if (lane == 0) sK = K0 + __popcll(aliveMask);
        }
        __syncthreads();
    }
    if (tid == 0) Kcnt[p] = sK;
}

// ---------------------------------------------------------------------------
// Kernel 3: k-means assignment (1 iter): each candidate (= masked point) finds
// nearest kept center (first-index tie-break via strict <, kept list is in
// ascending original index), accumulates sums/counts with atomics.
// ---------------------------------------------------------------------------
__global__ __launch_bounds__(256) void k_assign(
    const float* __restrict__ cand_x, const float* __restrict__ cand_y,
    const int* __restrict__ Mcnt,
    const float* __restrict__ kept_x, const float* __restrict__ kept_y,
    const int* __restrict__ kept_i, const int* __restrict__ Kcnt,
    float* __restrict__ sumx, float* __restrict__ sumy, float* __restrict__ cntw)
{
    int p = blockIdx.y;
    int idx = blockIdx.x * 256 + threadIdx.x;
    if (idx >= Mcnt[p]) return;
    int K = Kcnt[p];
    if (K == 0) return;   // no kept centers -> outputs are zero anyway
    int base = p * NPTS;
    float x = cand_x[base + idx], y = cand_y[base + idx];
    float bd = 1e30f;
    int bk = 0;
    for (int k = 0; k < K; ++k) {
        float dx = __fsub_rn(x, kept_x[base + k]);
        float dy = __fsub_rn(y, kept_y[base + k]);
        float d2 = __fadd_rn(__fmul_rn(dx, dx), __fmul_rn(dy, dy));
        if (d2 < bd) { bd = d2; bk = k; }
    }
    int gi = kept_i[base + bk];
    atomicAdd(&sumx[base + gi], x);
    atomicAdd(&sumy[base + gi], y);
    atomicAdd(&cntw[base + gi], 1.0f);
}

// ---------------------------------------------------------------------------
// Kernel 4: assemble outputs. centers [6,N,2] then keep [6,N], all written.
// ---------------------------------------------------------------------------
__global__ __launch_bounds__(256) void k_out(
    const float* __restrict__ lidar, const unsigned char* __restrict__ keepf,
    const float* __restrict__ sumx, const float* __restrict__ sumy,
    const float* __restrict__ cntw, float* __restrict__ out)
{
    int t = blockIdx.x * 256 + threadIdx.x;
    if (t >= NP * NPTS) return;
    int p = t / NPTS, n = t - p * NPTS;
    int b = p / 3;
    float ox = 0.f, oy = 0.f, kf = 0.f;
    if (keepf[t]) {
        kf = 1.f;
        float cw = cntw[t];
        if (cw > 0.f) {
            ox = sumx[t] / cw;   // max(cnt,1) == cnt when cnt >= 1
            oy = sumy[t] / cw;
        } else {                 // kept but empty cluster: original point
            ox = lidar[(size_t)b * 2 * NPTS + n];
            oy = lidar[(size_t)b * 2 * NPTS + NPTS + n];
        }
    }
    out[2 * t]     = ox;
    out[2 * t + 1] = oy;
    out[NP * NPTS * 2 + t] = kf;
}

// ---------------------------------------------------------------------------
extern "C" void kernel_launch(void* const* d_in, const int* in_sizes, int n_in,
                              void* d_out, int out_size, void* d_ws, size_t ws_size,
                              hipStream_t stream) {
    const float* seg   = (const float*)d_in[0];   // [B,C,H,W] f32
    const float* lidar = (const float*)d_in[1];   // [B,2,H,W] f32
    float* out = (float*)d_out;

    const size_t A = (size_t)NP * NPTS;           // 49152 entries
    char* ws = (char*)d_ws;
    float* sumx = (float*)ws;
    float* sumy = sumx + A;
    float* cntw = sumy + A;
    unsigned char* keepf = (unsigned char*)(cntw + A);
    float* cand_x = (float*)(keepf + A);
    float* cand_y = cand_x + A;
    int*   cand_i = (int*)(cand_y + A);
    float* kept_x = (float*)(cand_i + A);
    float* kept_y = kept_x + A;
    int*   kept_i = (int*)(kept_y + A);
    int*   Mcnt   = (int*)(kept_i + A);
    int*   Kcnt   = Mcnt + 64;
    // total ws use: ~1.74 MB

    // zero sums/counts + keep flags (contiguous region at ws start)
    hipMemsetAsync(ws, 0, 3 * A * sizeof(float) + A, stream);

    k_compact<<<NP, 1024, 0, stream>>>(seg, lidar, cand_x, cand_y, cand_i, Mcnt);
    k_nms<<<NP, 1024, 0, stream>>>(cand_x, cand_y, cand_i, Mcnt,
                                   kept_x, kept_y, kept_i, Kcnt, keepf);
    k_assign<<<dim3((NPTS + 255) / 256, NP), 256, 0, stream>>>(
        cand_x, cand_y, Mcnt, kept_x, kept_y, kept_i, Kcnt, sumx, sumy, cntw);
    k_out<<<(NP * NPTS + 255) / 256, 256, 0, stream>>>(
        lidar, keepf, sumx, sumy, cntw, out);
}

// Round 2
// 236.953 us; speedup vs baseline: 2.3532x; 2.3532x over previous
//
#include <hip/hip_runtime.h>

#define NPTS 8192      // H*W
#define BCLS 4         // C
#define NP   6         // B*(C-1) pairs
#define R2   9.0f
#define NBCAP 32       // neighbor-list capacity (overflow -> exact fallback)

#define ST_U 0
#define ST_A 1
#define ST_D 2

// ---------------------------------------------------------------------------
// Kernel 1: per (b,c) pair, argmax class + order-preserving compaction of
// candidate points (x, y, orig_index).  (unchanged from round 1 — passing)
// ---------------------------------------------------------------------------
__global__ __launch_bounds__(1024) void k_compact(
    const float* __restrict__ seg, const float* __restrict__ lidar,
    float* __restrict__ cand_x, float* __restrict__ cand_y,
    int* __restrict__ cand_i, int* __restrict__ Mcnt)
{
    int p = blockIdx.x;
    int b = p / 3, cls = p % 3 + 1;
    int tid = threadIdx.x;
    int lane = tid & 63, wave = tid >> 6;
    __shared__ int wsum[16];
    __shared__ int sbase;
    if (tid == 0) sbase = 0;
    __syncthreads();
    const float* segb = seg + (size_t)b * BCLS * NPTS;
    const float* lx = lidar + (size_t)b * 2 * NPTS;
    const float* ly = lx + NPTS;
    for (int start = 0; start < NPTS; start += 1024) {
        int n = start + tid;
        float bv = segb[n];
        int bc = 0;
        #pragma unroll
        for (int c2 = 1; c2 < BCLS; ++c2) {
            float v = segb[c2 * NPTS + n];
            if (v > bv) { bv = v; bc = c2; }
        }
        bool m = (bc == cls);
        unsigned long long bal = __ballot(m);
        int rank = __popcll(bal & ((1ull << lane) - 1ull));
        if (lane == 0) wsum[wave] = __popcll(bal);
        __syncthreads();
        if (tid == 0) {
            int acc = sbase;
            for (int w = 0; w < 16; ++w) { int t = wsum[w]; wsum[w] = acc; acc += t; }
            sbase = acc;
        }
        __syncthreads();
        if (m) {
            int pos = p * NPTS + wsum[wave] + rank;
            cand_x[pos] = lx[n];
            cand_y[pos] = ly[n];
            cand_i[pos] = n;
        }
        __syncthreads();
    }
    if (tid == 0) Mcnt[p] = sbase;
}

// ---------------------------------------------------------------------------
// Kernel 2: neighbor-list build. For each candidate i, record all j != i with
// d2(i,j) < R2, ascending j. Cap NBCAP entries; nb_cnt stores the TRUE count
// (cnt > NBCAP marks overflow -> exact fallback path downstream).
// Grid: (16, NP) blocks x 256 thr; block bp handles i = bp + 16*t (balanced).
// ---------------------------------------------------------------------------
__global__ __launch_bounds__(256) void k_neighbors(
    const float* __restrict__ cand_x, const float* __restrict__ cand_y,
    const int* __restrict__ Mcnt,
    unsigned int* __restrict__ nb_cnt, unsigned short* __restrict__ nb_idx)
{
    int p = blockIdx.y, bp = blockIdx.x;
    int M = Mcnt[p];
    __shared__ float2 sp[NPTS];   // 64 KB
    const int base = p * NPTS;
    for (int k = threadIdx.x; k < M; k += 256)
        sp[k] = make_float2(cand_x[base + k], cand_y[base + k]);
    __syncthreads();
    for (int r = 0; ; ++r) {
        int t = threadIdx.x + 256 * r;
        int i = bp + 16 * t;
        if (i >= M) break;
        float x = sp[i].x, y = sp[i].y;
        int cnt = 0;
        unsigned short* lst = nb_idx + (size_t)(base + i) * NBCAP;
        #pragma unroll 4
        for (int j = 0; j < M; ++j) {
            float dx = __fsub_rn(x, sp[j].x);
            float dy = __fsub_rn(y, sp[j].y);
            float d2 = __fadd_rn(__fmul_rn(dx, dx), __fmul_rn(dy, dy));
            if (d2 < R2 && j != i) {
                if (cnt < NBCAP) lst[cnt] = (unsigned short)j;
                cnt++;
            }
        }
        nb_cnt[base + i] = (unsigned int)cnt;
    }
}

// ---------------------------------------------------------------------------
// Kernel 3: chaotic fixed-point greedy-NMS resolve + k-means assignment.
// One block per pair. st[i]: U undecided / A alive(kept) / D dead.
//   round: undecided i -> if any ALIVE j<i in nb list: DEAD;
//          else if all j<i decided: ALIVE.  (least undecided always resolves
//          each round -> guaranteed termination; sparse graph -> ~few rounds)
// Then: each candidate assigns to nearest kept center. kept -> self (d2=0);
// suppressed -> its suppressor (kept, d2<R2) is in the nb list, and any kept
// center with d2>=R2 can't beat it, so scanning the nb list IS the global
// argmin (ascending index + strict < reproduces first-index tie-break).
// ---------------------------------------------------------------------------
__global__ __launch_bounds__(1024) void k_resolve_assign(
    const float* __restrict__ cand_x, const float* __restrict__ cand_y,
    const int* __restrict__ cand_i, const int* __restrict__ Mcnt,
    const unsigned int* __restrict__ nb_cnt, const unsigned short* __restrict__ nb_idx,
    unsigned char* __restrict__ keepf,
    float* __restrict__ sumx, float* __restrict__ sumy, float* __restrict__ cntw)
{
    int p = blockIdx.x;
    int tid = threadIdx.x;
    int M = Mcnt[p];
    const int base = p * NPTS;
    __shared__ float2 sp[NPTS];          // 64 KB
    __shared__ unsigned char st[NPTS];   // 8 KB
    __shared__ int srem;
    for (int k = tid; k < NPTS; k += 1024) st[k] = ST_U;
    for (int k = tid; k < M; k += 1024)
        sp[k] = make_float2(cand_x[base + k], cand_y[base + k]);
    __syncthreads();

    for (int round = 0; round < NPTS; ++round) {
        if (tid == 0) srem = 0;
        __syncthreads();
        int lrem = 0;
        for (int i = tid; i < M; i += 1024) {
            if (st[i] != ST_U) continue;
            unsigned int cnt = nb_cnt[base + i];
            bool dead = false, undec = false;
            if (cnt <= NBCAP) {
                const unsigned short* lst = nb_idx + (size_t)(base + i) * NBCAP;
                for (unsigned int e = 0; e < cnt; ++e) {
                    int j = lst[e];
                    if (j >= i) break;          // ascending: later entries are j > i
                    unsigned char s = st[j];
                    if (s == ST_A) { dead = true; break; }
                    if (s == ST_U) undec = true;
                }
            } else {                             // overflow: exact full scan
                float x = sp[i].x, y = sp[i].y;
                for (int j = 0; j < i; ++j) {
                    float dx = __fsub_rn(x, sp[j].x);
                    float dy = __fsub_rn(y, sp[j].y);
                    float d2 = __fadd_rn(__fmul_rn(dx, dx), __fmul_rn(dy, dy));
                    if (d2 < R2) {
                        unsigned char s = st[j];
                        if (s == ST_A) { dead = true; break; }
                        if (s == ST_U) undec = true;
                    }
                }
            }
            if (dead) st[i] = ST_D;
            else if (!undec) st[i] = ST_A;
            else lrem++;
        }
        if (lrem) atomicAdd(&srem, lrem);
        __syncthreads();
        if (srem == 0) break;
        __syncthreads();   // protect srem before next round's reset
    }

    // ---- assignment + accumulation ----
    for (int i = tid; i < M; i += 1024) {
        float x = sp[i].x, y = sp[i].y;
        int bj;
        if (st[i] == ST_A) {
            int gi = cand_i[base + i];
            keepf[base + gi] = 1;
            bj = i;                              // self: d2 = 0 is the unique min
        } else {
            unsigned int cnt = nb_cnt[base + i];
            float bd = 1e30f;
            bj = -1;
            if (cnt <= NBCAP) {
                const unsigned short* lst = nb_idx + (size_t)(base + i) * NBCAP;
                for (unsigned int e = 0; e < cnt; ++e) {
                    int j = lst[e];
                    if (st[j] != ST_A) continue;
                    float dx = __fsub_rn(x, sp[j].x);
                    float dy = __fsub_rn(y, sp[j].y);
                    float d2 = __fadd_rn(__fmul_rn(dx, dx), __fmul_rn(dy, dy));
                    if (d2 < bd) { bd = d2; bj = j; }
                }
            } else {                             // overflow: exact global argmin
                for (int j = 0; j < M; ++j) {
                    if (st[j] != ST_A) continue;
                    float dx = __fsub_rn(x, sp[j].x);
                    float dy = __fsub_rn(y, sp[j].y);
                    float d2 = __fadd_rn(__fmul_rn(dx, dx), __fmul_rn(dy, dy));
                    if (d2 < bd) { bd = d2; bj = j; }
                }
            }
            if (bj < 0) continue;                // only possible if K == 0
        }
        int gj = cand_i[base + bj];
        atomicAdd(&sumx[base + gj], x);
        atomicAdd(&sumy[base + gj], y);
        atomicAdd(&cntw[base + gj], 1.0f);
    }
}

// ---------------------------------------------------------------------------
// Kernel 4: assemble outputs. centers [6,N,2] then keep [6,N], all written.
// ---------------------------------------------------------------------------
__global__ __launch_bounds__(256) void k_out(
    const float* __restrict__ lidar, const unsigned char* __restrict__ keepf,
    const float* __restrict__ sumx, const float* __restrict__ sumy,
    const float* __restrict__ cntw, float* __restrict__ out)
{
    int t = blockIdx.x * 256 + threadIdx.x;
    if (t >= NP * NPTS) return;
    int p = t / NPTS, n = t - p * NPTS;
    int b = p / 3;
    float ox = 0.f, oy = 0.f, kf = 0.f;
    if (keepf[t]) {
        kf = 1.f;
        float cw = cntw[t];
        if (cw > 0.f) {
            ox = sumx[t] / cw;   // max(cnt,1) == cnt when cnt >= 1
            oy = sumy[t] / cw;
        } else {                 // kept but empty cluster (unreachable; safety)
            ox = lidar[(size_t)b * 2 * NPTS + n];
            oy = lidar[(size_t)b * 2 * NPTS + NPTS + n];
        }
    }
    out[2 * t]     = ox;
    out[2 * t + 1] = oy;
    out[NP * NPTS * 2 + t] = kf;
}

// ---------------------------------------------------------------------------
extern "C" void kernel_launch(void* const* d_in, const int* in_sizes, int n_in,
                              void* d_out, int out_size, void* d_ws, size_t ws_size,
                              hipStream_t stream) {
    const float* seg   = (const float*)d_in[0];   // [B,C,H,W] f32
    const float* lidar = (const float*)d_in[1];   // [B,2,H,W] f32
    float* out = (float*)d_out;

    const size_t A = (size_t)NP * NPTS;           // 49152 entries
    char* ws = (char*)d_ws;
    float* sumx = (float*)ws;
    float* sumy = sumx + A;
    float* cntw = sumy + A;
    unsigned char* keepf = (unsigned char*)(cntw + A);        // A bytes
    float* cand_x = (float*)(keepf + A);
    float* cand_y = cand_x + A;
    int*   cand_i = (int*)(cand_y + A);
    unsigned int*   nb_cnt = (unsigned int*)(cand_i + A);     // A u32
    unsigned short* nb_idx = (unsigned short*)(nb_cnt + A);   // A*NBCAP u16 (3.1 MB)
    int*   Mcnt = (int*)(nb_idx + A * NBCAP);
    // total ws use: ~4.6 MB

    // zero sums/counts + keep flags (contiguous region at ws start)
    hipMemsetAsync(ws, 0, 3 * A * sizeof(float) + A, stream);

    k_compact<<<NP, 1024, 0, stream>>>(seg, lidar, cand_x, cand_y, cand_i, Mcnt);
    k_neighbors<<<dim3(16, NP), 256, 0, stream>>>(cand_x, cand_y, Mcnt, nb_cnt, nb_idx);
    k_resolve_assign<<<NP, 1024, 0, stream>>>(cand_x, cand_y, cand_i, Mcnt,
                                              nb_cnt, nb_idx, keepf, sumx, sumy, cntw);
    k_out<<<(NP * NPTS + 255) / 256, 256, 0, stream>>>(
        lidar, keepf, sumx, sumy, cntw, out);
}

// Round 3
// 143.829 us; speedup vs baseline: 3.8769x; 1.6475x over previous
//
#include <hip/hip_runtime.h>

#define NPTS 8192      // H*W
#define BCLS 4         // C
#define NP   6         // B*(C-1) pairs
#define NB   2         // batches
#define NCH  32        // 256-wide chunks per image
#define R2   9.0f
#define SEGCAP 8       // neighbor-list capacity per j-segment (4 segments = 32 total)

#define ST_U 0
#define ST_A 1
#define ST_D 2

// ---------------------------------------------------------------------------
// Kernel 1a: per (batch, chunk-of-256), argmax class; for each fg class store
// the 4x64-bit ballot words + per-chunk candidate count.
// ---------------------------------------------------------------------------
__global__ __launch_bounds__(256) void k_mask(
    const float* __restrict__ seg,
    unsigned long long* __restrict__ maskw, int* __restrict__ chunk_cnt)
{
    int ch = blockIdx.x, b = blockIdx.y;
    int tid = threadIdx.x, lane = tid & 63, wv = tid >> 6;
    int n = ch * 256 + tid;
    const float* segb = seg + (size_t)b * BCLS * NPTS;
    float bv = segb[n];
    int bc = 0;
    #pragma unroll
    for (int c2 = 1; c2 < BCLS; ++c2) {
        float v = segb[c2 * NPTS + n];
        if (v > bv) { bv = v; bc = c2; }   // strict >: first index wins ties
    }
    __shared__ int cnts[3][4];
    #pragma unroll
    for (int ci = 0; ci < 3; ++ci) {
        unsigned long long bal = __ballot(bc == ci + 1);
        if (lane == 0) {
            maskw[(((size_t)(b * 3 + ci) * NCH) + ch) * 4 + wv] = bal;
            cnts[ci][wv] = __popcll(bal);
        }
    }
    __syncthreads();
    if (tid < 3)
        chunk_cnt[(b * 3 + tid) * NCH + ch] =
            cnts[tid][0] + cnts[tid][1] + cnts[tid][2] + cnts[tid][3];
}

// ---------------------------------------------------------------------------
// Kernel 1b: tiny exclusive scan of chunk counts per pair -> chunk bases, Mcnt.
// ---------------------------------------------------------------------------
__global__ __launch_bounds__(64) void k_scan(
    const int* __restrict__ chunk_cnt, int* __restrict__ chunk_base,
    int* __restrict__ Mcnt)
{
    int tid = threadIdx.x;
    if (tid < NP) {
        int acc = 0;
        for (int ch = 0; ch < NCH; ++ch) {
            chunk_base[tid * NCH + ch] = acc;
            acc += chunk_cnt[tid * NCH + ch];
        }
        Mcnt[tid] = acc;
    }
}

// ---------------------------------------------------------------------------
// Kernel 1c: scatter candidates (order-preserving) using ballot words.
// ---------------------------------------------------------------------------
__global__ __launch_bounds__(256) void k_scatter(
    const float* __restrict__ lidar,
    const unsigned long long* __restrict__ maskw, const int* __restrict__ chunk_base,
    float2* __restrict__ cxy, int* __restrict__ cand_i)
{
    int ch = blockIdx.x, p = blockIdx.y, b = p / 3;
    int tid = threadIdx.x, lane = tid & 63, wv = tid >> 6;
    __shared__ unsigned long long w[4];
    __shared__ int cbase;
    if (tid < 4) w[tid] = maskw[(((size_t)p * NCH) + ch) * 4 + tid];
    if (tid == 0) cbase = chunk_base[p * NCH + ch];
    __syncthreads();
    bool m = (w[wv] >> lane) & 1ull;
    if (m) {
        int r = __popcll(w[wv] & ((1ull << lane) - 1ull));
        for (int v = 0; v < wv; ++v) r += __popcll(w[v]);
        int n = ch * 256 + tid;
        int pos = p * NPTS + cbase + r;
        const float* lx = lidar + (size_t)b * 2 * NPTS;
        cxy[pos] = make_float2(lx[n], lx[NPTS + n]);
        cand_i[pos] = n;
    }
}

// ---------------------------------------------------------------------------
// Kernel 2: neighbor lists, j-split 4 ways. Block (bi, s, p): 256 i's (one per
// thread) x j in [s*Q, min((s+1)Q, M)), Q = ceil(M/4), staged in LDS.
// Segment lists (cap SEGCAP, ascending j) concatenate to a globally ascending
// list. True per-segment count saturated into byte s of nb_cnt[i];
// count > SEGCAP => consumers take the exact full-scan fallback.
// ---------------------------------------------------------------------------
__global__ __launch_bounds__(256) void k_neighbors(
    const float2* __restrict__ cxy, const int* __restrict__ Mcnt,
    unsigned int* __restrict__ nb_cnt, unsigned short* __restrict__ nb_idx)
{
    int bi = blockIdx.x, s = blockIdx.y, p = blockIdx.z;
    int tid = threadIdx.x;
    int M = Mcnt[p];
    int i0 = bi * 256;
    if (i0 >= M) return;                 // block-uniform: safe before barriers
    const int base = p * NPTS;
    int Q = (M + 3) >> 2;
    int j0 = s * Q, j1 = min(j0 + Q, M);
    __shared__ float2 sp[2048];          // 16 KB (Q <= 2048 always)
    for (int k = tid; k < j1 - j0; k += 256)
        sp[k] = cxy[base + j0 + k];
    __syncthreads();
    int i = i0 + tid;
    if (i < M) {
        float2 me = cxy[base + i];
        unsigned short* lst = nb_idx + (size_t)(base + i) * (4 * SEGCAP) + s * SEGCAP;
        int cnt = 0;
        for (int j = j0; j < j1; ++j) {
            float2 q = sp[j - j0];
            float dx = __fsub_rn(me.x, q.x), dy = __fsub_rn(me.y, q.y);
            float d2 = __fadd_rn(__fmul_rn(dx, dx), __fmul_rn(dy, dy));
            if (d2 < R2 && j != i) {
                if (cnt < SEGCAP) lst[cnt] = (unsigned short)j;
                cnt++;
            }
        }
        ((unsigned char*)nb_cnt)[(size_t)(base + i) * 4 + s] =
            (unsigned char)min(cnt, 255);
    }
}

// ---------------------------------------------------------------------------
// Kernel 3: chaotic fixed-point greedy-NMS resolve + k-means assignment.
// One block per pair. st[i]: U/A/D; each round an undecided i dies if any
// ALIVE j<i in its nb list, becomes ALIVE if all j<i decided non-alive.
// Least undecided index always resolves -> termination; sparse graph -> few
// rounds. Assignment: nearest kept center is within radius (self or
// suppressor), so the nb list scan IS the global argmin (ascending j +
// strict < reproduces jnp's first-index tie-break).
// ---------------------------------------------------------------------------
__global__ __launch_bounds__(1024) void k_resolve_assign(
    const float2* __restrict__ cxy, const int* __restrict__ cand_i,
    const int* __restrict__ Mcnt,
    const unsigned int* __restrict__ nb_cnt, const unsigned short* __restrict__ nb_idx,
    unsigned char* __restrict__ keepf,
    float* __restrict__ sumx, float* __restrict__ sumy, float* __restrict__ cntw)
{
    int p = blockIdx.x;
    int tid = threadIdx.x;
    int M = Mcnt[p];
    const int base = p * NPTS;
    __shared__ float2 sp[NPTS];          // 64 KB
    __shared__ unsigned char st[NPTS];   // 8 KB
    __shared__ int srem;
    for (int k = tid; k < NPTS; k += 1024) st[k] = ST_U;
    for (int k = tid; k < M; k += 1024) sp[k] = cxy[base + k];
    __syncthreads();

    for (int round = 0; round < NPTS; ++round) {
        if (tid == 0) srem = 0;
        __syncthreads();
        int lrem = 0;
        for (int i = tid; i < M; i += 1024) {
            if (st[i] != ST_U) continue;
            unsigned int cw = nb_cnt[base + i];
            bool ovf = ((cw & 255u) > SEGCAP) | (((cw >> 8) & 255u) > SEGCAP) |
                       (((cw >> 16) & 255u) > SEGCAP) | ((cw >> 24) > SEGCAP);
            bool dead = false, undec = false;
            if (!ovf) {
                const unsigned short* lst = nb_idx + (size_t)(base + i) * (4 * SEGCAP);
                bool stop = false;
                for (int s4 = 0; s4 < 4 && !stop; ++s4) {
                    int cs = (cw >> (8 * s4)) & 255;
                    for (int e = 0; e < cs; ++e) {
                        int j = lst[s4 * SEGCAP + e];
                        if (j >= i) { stop = true; break; }   // ascending
                        unsigned char sv = st[j];
                        if (sv == ST_A) { dead = true; stop = true; break; }
                        if (sv == ST_U) undec = true;
                    }
                }
            } else {                     // overflow: exact full scan
                float2 me = sp[i];
                for (int j = 0; j < i; ++j) {
                    float dx = __fsub_rn(me.x, sp[j].x);
                    float dy = __fsub_rn(me.y, sp[j].y);
                    float d2 = __fadd_rn(__fmul_rn(dx, dx), __fmul_rn(dy, dy));
                    if (d2 < R2) {
                        unsigned char sv = st[j];
                        if (sv == ST_A) { dead = true; break; }
                        if (sv == ST_U) undec = true;
                    }
                }
            }
            if (dead) st[i] = ST_D;
            else if (!undec) st[i] = ST_A;
            else lrem++;
        }
        if (lrem) atomicAdd(&srem, lrem);
        __syncthreads();
        if (srem == 0) break;
        __syncthreads();                 // protect srem before next reset
    }

    // ---- assignment + accumulation ----
    for (int i = tid; i < M; i += 1024) {
        float2 me = sp[i];
        int bj;
        if (st[i] == ST_A) {
            keepf[base + cand_i[base + i]] = 1;
            bj = i;                      // self: d2 = 0 is the unique min
        } else {
            unsigned int cw = nb_cnt[base + i];
            bool ovf = ((cw & 255u) > SEGCAP) | (((cw >> 8) & 255u) > SEGCAP) |
                       (((cw >> 16) & 255u) > SEGCAP) | ((cw >> 24) > SEGCAP);
            float bd = 1e30f;
            bj = -1;
            if (!ovf) {
                const unsigned short* lst = nb_idx + (size_t)(base + i) * (4 * SEGCAP);
                for (int s4 = 0; s4 < 4; ++s4) {
                    int cs = (cw >> (8 * s4)) & 255;
                    for (int e = 0; e < cs; ++e) {
                        int j = lst[s4 * SEGCAP + e];
                        if (st[j] != ST_A) continue;
                        float dx = __fsub_rn(me.x, sp[j].x);
                        float dy = __fsub_rn(me.y, sp[j].y);
                        float d2 = __fadd_rn(__fmul_rn(dx, dx), __fmul_rn(dy, dy));
                        if (d2 < bd) { bd = d2; bj = j; }
                    }
                }
            } else {                     // overflow: exact global argmin
                for (int j = 0; j < M; ++j) {
                    if (st[j] != ST_A) continue;
                    float dx = __fsub_rn(me.x, sp[j].x);
                    float dy = __fsub_rn(me.y, sp[j].y);
                    float d2 = __fadd_rn(__fmul_rn(dx, dx), __fmul_rn(dy, dy));
                    if (d2 < bd) { bd = d2; bj = j; }
                }
            }
            if (bj < 0) continue;        // only possible if K == 0 (then M == 0)
        }
        int gj = cand_i[base + bj];
        atomicAdd(&sumx[base + gj], me.x);
        atomicAdd(&sumy[base + gj], me.y);
        atomicAdd(&cntw[base + gj], 1.0f);
    }
}

// ---------------------------------------------------------------------------
// Kernel 4: assemble outputs. centers [6,N,2] then keep [6,N], all written.
// ---------------------------------------------------------------------------
__global__ __launch_bounds__(256) void k_out(
    const float* __restrict__ lidar, const unsigned char* __restrict__ keepf,
    const float* __restrict__ sumx, const float* __restrict__ sumy,
    const float* __restrict__ cntw, float* __restrict__ out)
{
    int t = blockIdx.x * 256 + threadIdx.x;
    if (t >= NP * NPTS) return;
    int p = t / NPTS, n = t - p * NPTS;
    int b = p / 3;
    float ox = 0.f, oy = 0.f, kf = 0.f;
    if (keepf[t]) {
        kf = 1.f;
        float cw = cntw[t];
        if (cw > 0.f) {
            ox = sumx[t] / cw;           // max(cnt,1) == cnt when cnt >= 1
            oy = sumy[t] / cw;
        } else {                         // unreachable safety
            ox = lidar[(size_t)b * 2 * NPTS + n];
            oy = lidar[(size_t)b * 2 * NPTS + NPTS + n];
        }
    }
    out[2 * t]     = ox;
    out[2 * t + 1] = oy;
    out[NP * NPTS * 2 + t] = kf;
}

// ---------------------------------------------------------------------------
extern "C" void kernel_launch(void* const* d_in, const int* in_sizes, int n_in,
                              void* d_out, int out_size, void* d_ws, size_t ws_size,
                              hipStream_t stream) {
    const float* seg   = (const float*)d_in[0];   // [B,C,H,W] f32
    const float* lidar = (const float*)d_in[1];   // [B,2,H,W] f32
    float* out = (float*)d_out;

    const size_t A = (size_t)NP * NPTS;           // 49152
    char* ws = (char*)d_ws;
    float* sumx = (float*)ws;                                  // 4A
    float* sumy = sumx + A;                                    // 4A
    float* cntw = sumy + A;                                    // 4A
    unsigned char* keepf = (unsigned char*)(cntw + A);         // A
    float2* cxy = (float2*)(keepf + A);                        // 8A (13A offset: 8B-aligned)
    int* cand_i = (int*)(cxy + A);                             // 4A
    unsigned int* nb_cnt = (unsigned int*)(cand_i + A);        // 4A
    unsigned short* nb_idx = (unsigned short*)(nb_cnt + A);    // 64A
    unsigned long long* maskw = (unsigned long long*)(nb_idx + A * 4 * SEGCAP); // 6 KB
    int* chunk_cnt = (int*)(maskw + (size_t)NP * NCH * 4);     // 768 B
    int* chunk_base = chunk_cnt + NP * NCH;                    // 768 B
    int* Mcnt = chunk_base + NP * NCH;                         // 256 B
    // total ws use: ~4.6 MB

    // zero sums/counts + keep flags (contiguous region at ws start)
    hipMemsetAsync(ws, 0, 3 * A * sizeof(float) + A, stream);

    k_mask<<<dim3(NCH, NB), 256, 0, stream>>>(seg, maskw, chunk_cnt);
    k_scan<<<1, 64, 0, stream>>>(chunk_cnt, chunk_base, Mcnt);
    k_scatter<<<dim3(NCH, NP), 256, 0, stream>>>(lidar, maskw, chunk_base, cxy, cand_i);
    k_neighbors<<<dim3(32, 4, NP), 256, 0, stream>>>(cxy, Mcnt, nb_cnt, nb_idx);
    k_resolve_assign<<<NP, 1024, 0, stream>>>(cxy, cand_i, Mcnt,
                                              nb_cnt, nb_idx, keepf, sumx, sumy, cntw);
    k_out<<<(NP * NPTS + 255) / 256, 256, 0, stream>>>(
        lidar, keepf, sumx, sumy, cntw, out);
}

// Round 4
// 140.844 us; speedup vs baseline: 3.9591x; 1.0212x over previous
//
#include <hip/hip_runtime.h>

#define NPTS 8192      // H*W
#define BCLS 4         // C
#define NP   6         // B*(C-1) pairs
#define R2   9.0f
#define SEG    8       // j-split segments in neighbor build
#define SEGCAP 4       // stored entries per segment (true count kept separately)
#define NBTOT  (SEG*SEGCAP)   // 32 stored neighbor slots per point
#define ECAP   3       // LDS-cached earlier-neighbor (j<i) prefix per point

#define ST_U 0
#define ST_A 1
#define ST_D 2

// ---------------------------------------------------------------------------
// Kernel 1: per pair — zero accumulators, argmax class, order-preserving
// compaction of candidates (proven round-1 structure, float2 output).
// ---------------------------------------------------------------------------
__global__ __launch_bounds__(1024) void k_compact(
    const float* __restrict__ seg, const float* __restrict__ lidar,
    float2* __restrict__ cxy, int* __restrict__ cand_i, int* __restrict__ Mcnt,
    float* __restrict__ sumx, float* __restrict__ sumy, float* __restrict__ cntw,
    unsigned char* __restrict__ keepf)
{
    int p = blockIdx.x;
    int b = p / 3, cls = p % 3 + 1;
    int tid = threadIdx.x;
    int lane = tid & 63, wave = tid >> 6;
    const int base = p * NPTS;
    // zero this pair's accumulator slices (replaces hipMemsetAsync)
    for (int k = tid; k < NPTS; k += 1024) {
        sumx[base + k] = 0.f; sumy[base + k] = 0.f; cntw[base + k] = 0.f;
        keepf[base + k] = 0;
    }
    __shared__ int wsum[16];
    __shared__ int sbase;
    if (tid == 0) sbase = 0;
    __syncthreads();
    const float* segb = seg + (size_t)b * BCLS * NPTS;
    const float* lx = lidar + (size_t)b * 2 * NPTS;
    const float* ly = lx + NPTS;
    for (int start = 0; start < NPTS; start += 1024) {
        int n = start + tid;
        float bv = segb[n];
        int bc = 0;
        #pragma unroll
        for (int c2 = 1; c2 < BCLS; ++c2) {
            float v = segb[c2 * NPTS + n];
            if (v > bv) { bv = v; bc = c2; }   // strict >: first index wins ties
        }
        bool m = (bc == cls);
        unsigned long long bal = __ballot(m);
        int rank = __popcll(bal & ((1ull << lane) - 1ull));
        if (lane == 0) wsum[wave] = __popcll(bal);
        __syncthreads();
        if (tid == 0) {
            int acc = sbase;
            for (int w = 0; w < 16; ++w) { int t = wsum[w]; wsum[w] = acc; acc += t; }
            sbase = acc;
        }
        __syncthreads();
        if (m) {
            int pos = base + wsum[wave] + rank;
            cxy[pos] = make_float2(lx[n], ly[n]);
            cand_i[pos] = n;
        }
        __syncthreads();
    }
    if (tid == 0) Mcnt[p] = sbase;
}

// ---------------------------------------------------------------------------
// Kernel 2: neighbor lists, j-split SEG ways. Block (bi, s, p): 256 i's (one
// per thread) x j in segment s (staged in LDS). Per-seg stored entries cap
// SEGCAP (ascending j; segment concat = globally ascending); TRUE per-seg
// count saturated into byte nb_scnt[(base+i)*SEG+s] (distinct bytes per
// block: no RMW hazard). Any seg count > SEGCAP => exact fallback downstream.
// ---------------------------------------------------------------------------
__global__ __launch_bounds__(256) void k_neighbors(
    const float2* __restrict__ cxy, const int* __restrict__ Mcnt,
    unsigned char* __restrict__ nb_scnt, unsigned short* __restrict__ nb_idx)
{
    int bi = blockIdx.x, s = blockIdx.y, p = blockIdx.z;
    int tid = threadIdx.x;
    int M = Mcnt[p];
    int i0 = bi * 256;
    if (i0 >= M) return;                 // block-uniform: safe before barriers
    const int base = p * NPTS;
    int Q = (M + SEG - 1) / SEG;
    int j0 = s * Q, j1 = min(j0 + Q, M);
    __shared__ float2 sp[1024];          // 8 KB (Q <= 8192/8 = 1024)
    for (int k = tid; k < j1 - j0; k += 256)
        sp[k] = cxy[base + j0 + k];
    __syncthreads();
    int i = i0 + tid;
    if (i < M) {
        float2 me = cxy[base + i];
        unsigned short* lst = nb_idx + (size_t)(base + i) * NBTOT + s * SEGCAP;
        int cnt = 0;
        for (int j = j0; j < j1; ++j) {
            float2 q = sp[j - j0];
            float dx = __fsub_rn(me.x, q.x), dy = __fsub_rn(me.y, q.y);
            float d2 = __fadd_rn(__fmul_rn(dx, dx), __fmul_rn(dy, dy));
            if (d2 < R2 && j != i) {
                if (cnt < SEGCAP) lst[cnt] = (unsigned short)j;
                cnt++;
            }
        }
        nb_scnt[(size_t)(base + i) * SEG + s] = (unsigned char)min(cnt, 255);
    }
}

// ---------------------------------------------------------------------------
// Kernel 3: fixed-point greedy-NMS resolve (LDS-only rounds) + assignment.
// Staging: per i, the j<i prefix of its ascending nb list (cap ECAP) into
// LDS; ecnt=255 marks seg-overflow => exact fallback. Rounds: one
// __syncthreads_count barrier each; undecided i dies if any ALIVE earlier
// neighbor, goes ALIVE when all earlier neighbors decided non-alive. Least
// undecided index always resolves => termination. Decisions only ever use
// finalized info => identical to sequential greedy. Assignment: nearest kept
// center is within radius (self or suppressor), so scanning the full nb list
// (ascending j + strict <) IS the global argmin incl. jnp tie-break.
// ---------------------------------------------------------------------------
__global__ __launch_bounds__(1024) void k_resolve_assign(
    const float2* __restrict__ cxy, const int* __restrict__ cand_i,
    const int* __restrict__ Mcnt,
    const unsigned char* __restrict__ nb_scnt, const unsigned short* __restrict__ nb_idx,
    unsigned char* __restrict__ keepf,
    float* __restrict__ sumx, float* __restrict__ sumy, float* __restrict__ cntw)
{
    int p = blockIdx.x;
    int tid = threadIdx.x;
    int M = Mcnt[p];
    const int base = p * NPTS;
    __shared__ unsigned short elist[NPTS * ECAP];   // 48 KB
    __shared__ unsigned char ecnt_s[NPTS];          // 8 KB (255 = overflow)
    __shared__ unsigned char st[NPTS];              // 8 KB

    // ---- stage earlier-neighbor prefixes ----
    for (int i = tid; i < M; i += 1024) {
        unsigned long long w =
            *(const unsigned long long*)(nb_scnt + (size_t)(base + i) * SEG);
        const unsigned short* lst = nb_idx + (size_t)(base + i) * NBTOT;
        bool ovf = false; int ec = 0, stored = 0; bool stop = false;
        for (int s = 0; s < SEG && !stop; ++s) {
            int cs = (int)((w >> (8 * s)) & 255ull);
            if (cs > SEGCAP) { ovf = true; break; }
            for (int e = 0; e < cs; ++e) {
                int j = lst[s * SEGCAP + e];
                if (j >= i) { stop = true; break; }      // ascending list
                if (stored < ECAP) { elist[i * ECAP + stored] = (unsigned short)j; stored++; }
                ec++;
            }
        }
        ecnt_s[i] = ovf ? 255 : (unsigned char)ec;       // ec <= 32
        st[i] = ST_U;
    }
    __syncthreads();

    // ---- rounds: LDS-only for the common case, one barrier each ----
    unsigned int pend = 0;
    for (int k = 0; k < 8; ++k)
        if (k * 1024 + tid < M) pend |= 1u << k;
    for (int round = 0; round < NPTS; ++round) {
        unsigned int np = 0;
        for (int k = 0; k < 8; ++k) {
            if (!(pend & (1u << k))) continue;
            int i = tid + (k << 10);
            unsigned char ec = ecnt_s[i];
            bool dead = false, undec = false;
            if (ec != 255) {
                int lim = ec < ECAP ? ec : ECAP;
                for (int e = 0; e < lim; ++e) {
                    unsigned char sv = st[elist[i * ECAP + e]];
                    if (sv == ST_A) { dead = true; break; }
                    if (sv == ST_U) undec = true;
                }
                if (!dead && ec > ECAP) {   // rare: continuation from global (cached)
                    unsigned long long w =
                        *(const unsigned long long*)(nb_scnt + (size_t)(base + i) * SEG);
                    const unsigned short* lst = nb_idx + (size_t)(base + i) * NBTOT;
                    int c2 = 0; bool stop = false;
                    for (int s = 0; s < SEG && !stop; ++s) {
                        int cs = (int)((w >> (8 * s)) & 255ull);
                        for (int e = 0; e < cs; ++e) {
                            int j = lst[s * SEGCAP + e];
                            if (j >= i) { stop = true; break; }
                            if (++c2 <= ECAP) continue;
                            unsigned char sv = st[j];
                            if (sv == ST_A) { dead = true; stop = true; break; }
                            if (sv == ST_U) undec = true;
                        }
                    }
                }
            } else {                        // seg overflow: exact scan (never in practice)
                float2 me = cxy[base + i];
                for (int j = 0; j < i; ++j) {
                    float2 q = cxy[base + j];
                    float dx = __fsub_rn(me.x, q.x), dy = __fsub_rn(me.y, q.y);
                    float d2 = __fadd_rn(__fmul_rn(dx, dx), __fmul_rn(dy, dy));
                    if (d2 < R2) {
                        unsigned char sv = st[j];
                        if (sv == ST_A) { dead = true; break; }
                        if (sv == ST_U) undec = true;
                    }
                }
            }
            if (dead) st[i] = ST_D;
            else if (!undec) st[i] = ST_A;
            else np |= 1u << k;
        }
        pend = np;
        if (__syncthreads_count(pend != 0) == 0) break;
    }

    // ---- assignment + accumulation ----
    for (int i = tid; i < M; i += 1024) {
        float2 me = cxy[base + i];
        int bj;
        if (st[i] == ST_A) {
            keepf[base + cand_i[base + i]] = 1;
            bj = i;                         // self: d2 = 0 is the unique min
        } else {
            unsigned long long w =
                *(const unsigned long long*)(nb_scnt + (size_t)(base + i) * SEG);
            bool ovf = false;
            for (int s = 0; s < SEG; ++s)
                if (((w >> (8 * s)) & 255ull) > SEGCAP) ovf = true;
            float bd = 1e30f;
            bj = -1;
            if (!ovf) {
                const unsigned short* lst = nb_idx + (size_t)(base + i) * NBTOT;
                for (int s = 0; s < SEG; ++s) {
                    int cs = (int)((w >> (8 * s)) & 255ull);
                    for (int e = 0; e < cs; ++e) {
                        int j = lst[s * SEGCAP + e];
                        if (st[j] != ST_A) continue;
                        float2 q = cxy[base + j];
                        float dx = __fsub_rn(me.x, q.x), dy = __fsub_rn(me.y, q.y);
                        float d2 = __fadd_rn(__fmul_rn(dx, dx), __fmul_rn(dy, dy));
                        if (d2 < bd) { bd = d2; bj = j; }   // ascending + strict <
                    }
                }
            } else {                        // exact global argmin over kept
                for (int j = 0; j < M; ++j) {
                    if (st[j] != ST_A) continue;
                    float2 q = cxy[base + j];
                    float dx = __fsub_rn(me.x, q.x), dy = __fsub_rn(me.y, q.y);
                    float d2 = __fadd_rn(__fmul_rn(dx, dx), __fmul_rn(dy, dy));
                    if (d2 < bd) { bd = d2; bj = j; }
                }
            }
            if (bj < 0) continue;           // K == 0: outputs stay zero
        }
        int gj = cand_i[base + bj];
        atomicAdd(&sumx[base + gj], me.x);
        atomicAdd(&sumy[base + gj], me.y);
        atomicAdd(&cntw[base + gj], 1.0f);
    }
}

// ---------------------------------------------------------------------------
// Kernel 4: assemble outputs. centers [6,N,2] then keep [6,N], all written.
// ---------------------------------------------------------------------------
__global__ __launch_bounds__(256) void k_out(
    const float* __restrict__ lidar, const unsigned char* __restrict__ keepf,
    const float* __restrict__ sumx, const float* __restrict__ sumy,
    const float* __restrict__ cntw, float* __restrict__ out)
{
    int t = blockIdx.x * 256 + threadIdx.x;
    if (t >= NP * NPTS) return;
    int p = t / NPTS, n = t - p * NPTS;
    int b = p / 3;
    float ox = 0.f, oy = 0.f, kf = 0.f;
    if (keepf[t]) {
        kf = 1.f;
        float cw = cntw[t];
        if (cw > 0.f) {
            ox = sumx[t] / cw;              // max(cnt,1) == cnt when cnt >= 1
            oy = sumy[t] / cw;
        } else {                            // unreachable safety
            ox = lidar[(size_t)b * 2 * NPTS + n];
            oy = lidar[(size_t)b * 2 * NPTS + NPTS + n];
        }
    }
    out[2 * t]     = ox;
    out[2 * t + 1] = oy;
    out[NP * NPTS * 2 + t] = kf;
}

// ---------------------------------------------------------------------------
extern "C" void kernel_launch(void* const* d_in, const int* in_sizes, int n_in,
                              void* d_out, int out_size, void* d_ws, size_t ws_size,
                              hipStream_t stream) {
    const float* seg   = (const float*)d_in[0];   // [B,C,H,W] f32
    const float* lidar = (const float*)d_in[1];   // [B,2,H,W] f32
    float* out = (float*)d_out;

    const size_t A = (size_t)NP * NPTS;           // 49152
    char* ws = (char*)d_ws;
    float* sumx = (float*)ws;                                  // 4A
    float* sumy = sumx + A;                                    // 4A
    float* cntw = sumy + A;                                    // 4A
    unsigned char* keepf = (unsigned char*)(cntw + A);         // A
    float2* cxy = (float2*)(keepf + A);                        // 8A (offset 13A: 8B-aligned)
    int* cand_i = (int*)(cxy + A);                             // 4A
    unsigned char* nb_scnt = (unsigned char*)(cand_i + A);     // 8A (offset 25A: 8B-aligned)
    unsigned short* nb_idx = (unsigned short*)(nb_scnt + A * SEG); // 64A
    int* Mcnt = (int*)(nb_idx + A * NBTOT);                    // 256 B
    // total ws use: ~4.8 MB

    k_compact<<<NP, 1024, 0, stream>>>(seg, lidar, cxy, cand_i, Mcnt,
                                       sumx, sumy, cntw, keepf);
    k_neighbors<<<dim3(32, SEG, NP), 256, 0, stream>>>(cxy, Mcnt, nb_scnt, nb_idx);
    k_resolve_assign<<<NP, 1024, 0, stream>>>(cxy, cand_i, Mcnt,
                                              nb_scnt, nb_idx, keepf, sumx, sumy, cntw);
    k_out<<<(NP * NPTS + 255) / 256, 256, 0, stream>>>(
        lidar, keepf, sumx, sumy, cntw, out);
}